// Round 11
// baseline (678.948 us; speedup 1.0000x reference)
//
#include <hip/hip_runtime.h>
#include <math.h>

#define BB 32
#define LL 40
#define DD 128
#define NSB 64                        // 2 seq * 32 batch
#define NU  (NSB * LL)                // 2560
#define PLANE (DD * DD)               // 16384
#define SLAB ((size_t)NSB * PLANE)    // u16 elements per t-slab (2 MB)
#define GMAXR 32                      // gate scratch sized for 32 rows

typedef unsigned short u16;
typedef unsigned int u32;

__device__ __forceinline__ u16 f2bf(float f) {
    union { float f; unsigned u; } v; v.f = f;
    unsigned u = v.u;
    u += 0x7fff + ((u >> 16) & 1);    // RNE
    return (u16)(u >> 16);
}
__device__ __forceinline__ float bf2f(u16 b) {
    union { unsigned u; float f; } v; v.u = ((unsigned)b) << 16;
    return v.f;
}
__device__ __forceinline__ float sigm(float x)  { return 1.f / (1.f + __expf(-x)); }
// tanh(x) = 2*sigmoid(2x)-1 ; safe at extremes
__device__ __forceinline__ float tanhs(float x) { return 2.f / (1.f + __expf(-2.f * x)) - 1.f; }

// ---------------- prep: xe rows + inverse squared norms ----------------
__global__ void prep_kernel(const int* __restrict__ q, const int* __restrict__ a,
                            const float* __restrict__ embed,
                            float* __restrict__ xe_all, float* __restrict__ inv_all) {
    int u = blockIdx.x * 4 + (threadIdx.x >> 6);
    int lane = threadIdx.x & 63;
    if (u >= NU) return;
    int sb = u / LL, t = u % LL;
    int s = sb >> 5, b = sb & 31;
    const int* idx = s ? a : q;
    int e = idx[b * LL + t];
    const float* row = embed + (size_t)e * DD;
    float v0 = row[lane], v1 = row[lane + 64];
    xe_all[(size_t)u * DD + lane] = v0;
    xe_all[(size_t)u * DD + lane + 64] = v1;
    float d = v0 * v0 + v1 * v1;
    #pragma unroll
    for (int o = 32; o; o >>= 1) d += __shfl_down(d, o);
    if (lane == 0) inv_all[u] = 1.f / (d + 1e-4f);
}

// ---------------- layer1 separable gates (xt-only rows, density rank-1) ----------------
// t-parallel: grid (LL, NSB), block 1024. Level rows [r0, r0+nr), all < 63.
// Writes packed (fg|og<<16) u32 plane and packed ic pairs.
__global__ __launch_bounds__(1024)
void sepgates_kernel(const float* __restrict__ xe_all, const float* __restrict__ inv_all,
                     const float* __restrict__ conv_w, const float* __restrict__ conv_b,
                     u32* __restrict__ gfo, u32* __restrict__ gic2,
                     int r0, int nr) {
    const int t = blockIdx.x, sb = blockIdx.y;
    const int tid = threadIdx.x;
    __shared__ float xe_s[132];        // data at [c+1], pads 0
    __shared__ float U[GMAXR][12];
    __shared__ float wls[48];
    float b4[4];
    #pragma unroll
    for (int k = 0; k < 4; ++k) b4[k] = conv_b[k];
    if (tid < 48) wls[tid] = conv_w[tid];
    if (tid < 128) xe_s[tid + 1] = xe_all[((size_t)sb * LL + t) * DD + tid];
    if (tid == 128) { xe_s[0] = 0.f; xe_s[129] = 0.f; xe_s[130] = 0.f; }
    __syncthreads();
    for (int e = tid; e < nr * 12; e += 1024) {
        int lr = e / 12, k = e - lr * 12;
        int g = k / 3, kw = k - g * 3;
        int base = 2 * (r0 + lr) - 1;
        float s = 0.f;
        #pragma unroll
        for (int kh = 0; kh < 4; ++kh) {
            int r = base + kh;
            float v = (r >= 0 && r < 128) ? xe_s[r + 1] : 0.f;
            s += wls[g * 12 + kh * 3 + kw] * v;
        }
        U[lr][k] = s;
    }
    __syncthreads();
    const float invv = inv_all[sb * LL + t];
    const size_t gb = (size_t)(t * NSB + sb) * ((size_t)nr * DD);
    const int nunits = nr * 64;
    for (int u = tid; u < nunits; u += 1024) {
        int lr = u >> 6, cp = u & 63;
        float x0 = xe_s[2 * cp], x1 = xe_s[2 * cp + 1];
        float x2 = xe_s[2 * cp + 2], x3 = xe_s[2 * cp + 3];
        float a[4], c[4];
        #pragma unroll
        for (int g = 0; g < 4; ++g) {
            float u0 = U[lr][g * 3], u1 = U[lr][g * 3 + 1], u2 = U[lr][g * 3 + 2];
            a[g] = b4[g] + invv * (u0 * x0 + u1 * x1 + u2 * x2);
            c[g] = b4[g] + invv * (u0 * x1 + u1 * x2 + u2 * x3);
        }
        float fg0 = sigm(a[0]), ic0 = sigm(a[1]) * tanhs(a[3]), og0 = sigm(a[2]);
        float fg1 = sigm(c[0]), ic1 = sigm(c[1]) * tanhs(c[3]), og1 = sigm(c[2]);
        const int px0 = lr * DD + 2 * cp;
        u32 f0 = (u32)f2bf(fg0) | ((u32)f2bf(og0) << 16);
        u32 f1 = (u32)f2bf(fg1) | ((u32)f2bf(og1) << 16);
        *(uint2*)&gfo[gb + px0] = make_uint2(f0, f1);
        gic2[(gb >> 1) + (px0 >> 1)] = (u32)f2bf(ic0) | ((u32)f2bf(ic1) << 16);
    }
}

// ---------------- generic gates: stage concat window into LDS, conv, pack ----------------
// t-parallel: grid (LL, NSB), block 1024. Level rows [r0, r0+nr), nr<=32.
// Concat row cr: cr<128 -> xt at time t (layer1: density; layer2: h1[t]);
//                cr>=128 -> own h row cr-128 at time t-1 (= slab t; slab 0 zeroed).
__global__ __launch_bounds__(1024)
void gates_kernel(const float* __restrict__ xe_all, const float* __restrict__ inv_all,
                  const float* __restrict__ conv_w, const float* __restrict__ conv_b,
                  const u16* __restrict__ xt_h1,   // layer2: h1 base; layer1: null (density)
                  const u16* __restrict__ h_own,
                  u32* __restrict__ gfo, u32* __restrict__ gic2,
                  int layer, int r0, int nr) {
    const int t = blockIdx.x, sb = blockIdx.y;
    const int tid = threadIdx.x;
    const int rfirst = 2 * r0 - 1, rcount = 2 * nr + 2;
    __shared__ float win[66][132];     // data col c at [c+2]; pads [0..1],[130..131] zero
    __shared__ float xe_s[128];
    float w[48], b4[4];                // uniform -> scalar regs
    #pragma unroll
    for (int k = 0; k < 48; ++k) w[k] = conv_w[layer * 48 + k];
    #pragma unroll
    for (int k = 0; k < 4; ++k) b4[k] = conv_b[layer * 4 + k];
    float invv = 0.f;
    if (layer == 0) {
        for (int e = tid; e < 128; e += 1024)
            xe_s[e] = xe_all[((size_t)sb * LL + t) * DD + e];
        invv = inv_all[sb * LL + t];
    }
    for (int e = tid; e < rcount; e += 1024) {
        win[e][0] = 0.f; win[e][1] = 0.f; win[e][130] = 0.f; win[e][131] = 0.f;
    }
    __syncthreads();                   // xe_s ready
    const u16* xt_base  = xt_h1 ? xt_h1 + (size_t)(t + 1) * SLAB + (size_t)sb * PLANE : nullptr;
    const u16* own_base = h_own + (size_t)t * SLAB + (size_t)sb * PLANE;
    for (int e = tid; e < rcount * 64; e += 1024) {
        int lr = e >> 6, cp = e & 63, cr = rfirst + lr;
        float v0 = 0.f, v1 = 0.f;
        if (cr >= 0) {
            if (cr < 128) {
                if (layer == 0) {
                    float xr = xe_s[cr] * invv;
                    v0 = xr * xe_s[2 * cp]; v1 = xr * xe_s[2 * cp + 1];
                } else {
                    u32 p = *(const u32*)(xt_base + (size_t)cr * DD + 2 * cp);
                    v0 = bf2f((u16)p); v1 = bf2f((u16)(p >> 16));
                }
            } else {
                u32 p = *(const u32*)(own_base + (size_t)(cr - 128) * DD + 2 * cp);
                v0 = bf2f((u16)p); v1 = bf2f((u16)(p >> 16));
            }
        }
        *(float2*)&win[lr][2 * cp + 2] = make_float2(v0, v1);
    }
    __syncthreads();
    const size_t gb = (size_t)(t * NSB + sb) * ((size_t)nr * DD);
    const int nunits = nr * 64;
    for (int u = tid; u < nunits; u += 1024) {
        const int lro = u >> 6, cp = u & 63;
        float a0 = b4[0], a1 = b4[1], a2 = b4[2], a3 = b4[3];
        float c0 = b4[0], c1 = b4[1], c2 = b4[2], c3 = b4[3];
        #pragma unroll
        for (int kh = 0; kh < 4; ++kh) {
            const float* wr = win[2 * lro + kh];
            float2 pA = *(const float2*)&wr[2 * cp];       // cols 2cp-2, 2cp-1
            float2 pB = *(const float2*)&wr[2 * cp + 2];   // cols 2cp, 2cp+1
            float  pC = wr[2 * cp + 4];                    // col 2cp+2
            a0 = fmaf(pA.y, w[kh*3+0], a0); a0 = fmaf(pB.x, w[kh*3+1], a0); a0 = fmaf(pB.y, w[kh*3+2], a0);
            a1 = fmaf(pA.y, w[12+kh*3+0], a1); a1 = fmaf(pB.x, w[12+kh*3+1], a1); a1 = fmaf(pB.y, w[12+kh*3+2], a1);
            a2 = fmaf(pA.y, w[24+kh*3+0], a2); a2 = fmaf(pB.x, w[24+kh*3+1], a2); a2 = fmaf(pB.y, w[24+kh*3+2], a2);
            a3 = fmaf(pA.y, w[36+kh*3+0], a3); a3 = fmaf(pB.x, w[36+kh*3+1], a3); a3 = fmaf(pB.y, w[36+kh*3+2], a3);
            c0 = fmaf(pB.x, w[kh*3+0], c0); c0 = fmaf(pB.y, w[kh*3+1], c0); c0 = fmaf(pC, w[kh*3+2], c0);
            c1 = fmaf(pB.x, w[12+kh*3+0], c1); c1 = fmaf(pB.y, w[12+kh*3+1], c1); c1 = fmaf(pC, w[12+kh*3+2], c1);
            c2 = fmaf(pB.x, w[24+kh*3+0], c2); c2 = fmaf(pB.y, w[24+kh*3+1], c2); c2 = fmaf(pC, w[24+kh*3+2], c2);
            c3 = fmaf(pB.x, w[36+kh*3+0], c3); c3 = fmaf(pB.y, w[36+kh*3+1], c3); c3 = fmaf(pC, w[36+kh*3+2], c3);
        }
        float fg0 = sigm(a0), ic0 = sigm(a1) * tanhs(a3), og0 = sigm(a2);
        float fg1 = sigm(c0), ic1 = sigm(c1) * tanhs(c3), og1 = sigm(c2);
        const int px0 = lro * DD + 2 * cp;
        u32 f0 = (u32)f2bf(fg0) | ((u32)f2bf(og0) << 16);
        u32 f1 = (u32)f2bf(fg1) | ((u32)f2bf(og1) << 16);
        *(uint2*)&gfo[gb + px0] = make_uint2(f0, f1);
        gic2[(gb >> 1) + (px0 >> 1)] = (u32)f2bf(ic0) | ((u32)f2bf(ic1) << 16);
    }
}

// ---------------- scan: pointwise c-recurrence over t ----------------
// grid (nr, NSB), block 128 (one row per block). h slab s holds time s-1.
__global__ __launch_bounds__(128)
void scan_kernel(const u32* __restrict__ gfo, const u16* __restrict__ gic,
                 u16* __restrict__ h, float* __restrict__ pool, int r0, int nr) {
    const int lr = blockIdx.x, sb = blockIdx.y, c = threadIdx.x;
    const size_t step = (size_t)NSB * nr * DD;
    size_t gi = ((size_t)sb * nr + lr) * DD + c;
    u16* hp = h + SLAB + (size_t)sb * PLANE + (size_t)(r0 + lr) * DD + c;
    float cc = 0.f, pr = -1e30f;
    #pragma unroll 4
    for (int t = 0; t < LL; ++t) {
        u32 v = gfo[gi];
        float fg = bf2f((u16)v), og = bf2f((u16)(v >> 16));
        float ic = bf2f(gic[gi]);
        cc = fg * cc + ic;
        float hn = og * tanhs(cc);
        *hp = f2bf(hn);
        pr = fmaxf(pr, hn);
        gi += step; hp += SLAB;
    }
    if (pool) pool[(size_t)sb * PLANE + (size_t)(r0 + lr) * DD + c] = pr;
}

// conv+LSTM update for one tail pixel from the LDS window
__device__ __forceinline__
float tail_px(const float (*wp)[130], const float* wls, const float* bls,
              int lr, int c, float& creg, float& pr) {
    float a0 = bls[0], a1 = bls[1], a2 = bls[2], a3 = bls[3];
    #pragma unroll
    for (int kh = 0; kh < 4; ++kh) {
        #pragma unroll
        for (int kw = 0; kw < 3; ++kw) {
            float v = wp[lr + kh][c + kw];
            a0 = fmaf(v, wls[kh*3+kw], a0);
            a1 = fmaf(v, wls[12+kh*3+kw], a1);
            a2 = fmaf(v, wls[24+kh*3+kw], a2);
            a3 = fmaf(v, wls[36+kh*3+kw], a3);
        }
    }
    float fg = sigm(a0), ig = sigm(a1), og = sigm(a2), cs = tanhs(a3);
    creg = fg * creg + ig * cs;
    float hn = og * tanhs(creg);
    pr = fmaxf(pr, hn);
    return hn;
}

// ---------------- tail rows 111..127: serial t, own rows in LDS ping-pong ----------------
// grid (NSB) x 1024. Window concat h rows 93..128 local; rows 93..110 staged from
// global each t (time t-1 = slab t), rows 111..127 from previous iteration's LDS.
__global__ __launch_bounds__(1024)
void tail_kernel(const u16* __restrict__ hsrc, u16* __restrict__ hdst,
                 float* __restrict__ pool,
                 const float* __restrict__ conv_w, const float* __restrict__ conv_b,
                 int layer) {
    const int sb = blockIdx.x;
    const int tid = threadIdx.x;
    __shared__ float win[2][36][130];   // local row lr = h_row - 93; lr 35 = zero pad
    __shared__ float wls[48], bls[4];
    if (tid < 48) wls[tid] = conv_w[layer * 48 + tid];
    if (tid < 4)  bls[tid] = conv_b[layer * 4 + tid];
    for (int e = tid; e < 2 * 36 * 130; e += 1024) ((float*)win)[e] = 0.f;

    const int c = tid & 127;
    const int rA = 111 + (tid >> 7);    // rows 111..118
    const int rB = rA + 8;              // rows 119..126
    const bool hasC = (tid < 128);      // row 127
    const int lrA = 2 * rA - 222;       // window start rows (local)
    const int lrB = 2 * rB - 222;
    const int lrC = 32;
    float cA = 0.f, cB = 0.f, cC = 0.f;
    float pA = -1e30f, pB = -1e30f, pC = -1e30f;

    for (int t = 0; t < LL; ++t) {
        const int p = t & 1;
        const u16* g = hsrc + (size_t)t * SLAB + (size_t)sb * PLANE + (size_t)93 * DD;
        __syncthreads();                      // prev compute done (reads of win[p] finished)
        for (int e = tid; e < 18 * 128; e += 1024)
            win[p][e >> 7][(e & 127) + 1] = bf2f(g[e]);
        __syncthreads();
        u16* hd = hdst ? hdst + (size_t)(t + 1) * SLAB + (size_t)sb * PLANE : nullptr;
        float hnA = tail_px(win[p], wls, bls, lrA, c, cA, pA);
        float hnB = tail_px(win[p], wls, bls, lrB, c, cB, pB);
        win[p ^ 1][18 + (rA - 111)][c + 1] = hnA;
        win[p ^ 1][18 + (rB - 111)][c + 1] = hnB;
        if (hd) {
            hd[(size_t)rA * DD + c] = f2bf(hnA);
            hd[(size_t)rB * DD + c] = f2bf(hnB);
        }
        if (hasC) {
            float hnC = tail_px(win[p], wls, bls, lrC, c, cC, pC);
            win[p ^ 1][34][c + 1] = hnC;
            if (hd) hd[(size_t)127 * DD + c] = f2bf(hnC);
        }
    }
    if (pool) {
        float* pb = pool + (size_t)sb * PLANE;
        pb[(size_t)rA * DD + c] = pA;
        pb[(size_t)rB * DD + c] = pB;
        if (hasC) pb[(size_t)127 * DD + c] = pC;
    }
}

// ---------------- final: linear + log_softmax ----------------
__global__ void final_kernel(const float* __restrict__ pool,
                             const float* __restrict__ lin_w,
                             const float* __restrict__ lin_b,
                             float* __restrict__ out) {
    const int b = blockIdx.x;
    const int tid = threadIdx.x;  // 256
    const int DD2 = DD * DD;
    const float* pq = pool + (size_t)b * DD2;
    const float* pa = pool + (size_t)(BB + b) * DD2;
    float s0 = 0.f, s1 = 0.f;
    for (int j = tid; j < DD2; j += 256) {
        float vq = pq[j], va = pa[j];
        s0 += vq * lin_w[j]           + va * lin_w[DD2 + j];
        s1 += vq * lin_w[2 * DD2 + j] + va * lin_w[3 * DD2 + j];
    }
    #pragma unroll
    for (int o = 32; o; o >>= 1) {
        s0 += __shfl_down(s0, o);
        s1 += __shfl_down(s1, o);
    }
    __shared__ float sh0[4], sh1[4];
    int wid = tid >> 6, lane = tid & 63;
    if (lane == 0) { sh0[wid] = s0; sh1[wid] = s1; }
    __syncthreads();
    if (tid == 0) {
        float a0 = sh0[0] + sh0[1] + sh0[2] + sh0[3] + lin_b[0];
        float a1 = sh1[0] + sh1[1] + sh1[2] + sh1[3] + lin_b[1];
        float m = fmaxf(a0, a1);
        float lse = m + logf(expf(a0 - m) + expf(a1 - m));
        out[b * 2 + 0] = a0 - lse;
        out[b * 2 + 1] = a1 - lse;
    }
}

extern "C" void kernel_launch(void* const* d_in, const int* in_sizes, int n_in,
                              void* d_out, int out_size, void* d_ws, size_t ws_size,
                              hipStream_t stream) {
    const int*   q      = (const int*)d_in[0];
    const int*   a      = (const int*)d_in[1];
    const float* embed  = (const float*)d_in[2];
    const float* conv_w = (const float*)d_in[3];
    const float* conv_b = (const float*)d_in[4];
    const float* lin_w  = (const float*)d_in[5];
    const float* lin_b  = (const float*)d_in[6];
    float* out = (float*)d_out;

    // ws: pool 4.2 | xe 1.31 | inv | h1 86 | h2 86 | gfo 41.9 | gic 21  => ~240.4 MB
    float* ws      = (float*)d_ws;
    float* pool    = ws;
    float* xe_all  = pool + (size_t)NSB * PLANE;
    float* inv_all = xe_all + (size_t)NU * DD;
    u16*   h1      = (u16*)(inv_all + NU);
    u16*   h2      = h1 + (size_t)(LL + 1) * SLAB;
    u32*   gfo     = (u32*)(h2 + (size_t)(LL + 1) * SLAB);
    u32*   gic2    = gfo + (size_t)LL * NSB * GMAXR * DD;
    const u16* gic = (const u16*)gic2;

    // zero the t = -1 slabs
    hipMemsetAsync(h1, 0, SLAB * sizeof(u16), stream);
    hipMemsetAsync(h2, 0, SLAB * sizeof(u16), stream);

    prep_kernel<<<(NU + 3) / 4, 256, 0, stream>>>(q, a, embed, xe_all, inv_all);

    // Levels [0,32) [32,63) [63,95) [95,111); rows 111..127 in one serial tail.
    const int levs[4][2] = {{0,32},{32,31},{63,32},{95,16}};
    const dim3 ggrid(LL, NSB);

    for (int layer = 0; layer < 2; ++layer) {
        const u16* xt = layer ? h1 : nullptr;
        u16* hh       = layer ? h2 : h1;
        float* pl     = layer ? pool : nullptr;
        for (int k = 0; k < 4; ++k) {
            const int r0 = levs[k][0], nr = levs[k][1];
            if (layer == 0 && k < 2) {
                sepgates_kernel<<<ggrid, 1024, 0, stream>>>(
                    xe_all, inv_all, conv_w, conv_b, gfo, gic2, r0, nr);
            } else {
                gates_kernel<<<ggrid, 1024, 0, stream>>>(
                    xe_all, inv_all, conv_w, conv_b, xt, hh,
                    gfo, gic2, layer, r0, nr);
            }
            scan_kernel<<<dim3(nr, NSB), 128, 0, stream>>>(
                gfo, gic, hh, pl, r0, nr);
        }
        tail_kernel<<<NSB, 1024, 0, stream>>>(hh, layer ? nullptr : h1,
                                              pl, conv_w, conv_b, layer);
    }

    final_kernel<<<BB, 256, 0, stream>>>(pool, lin_w, lin_b, out);
}

// Round 12
// 619.642 us; speedup vs baseline: 1.0957x; 1.0957x over previous
//
#include <hip/hip_runtime.h>
#include <math.h>

#define BB 32
#define LL 40
#define DD 128
#define NSB 64                        // 2 seq * 32 batch
#define NU  (NSB * LL)                // 2560
#define PLANE (DD * DD)               // 16384
#define SLAB ((size_t)NSB * PLANE)    // u16 elements per t-slab (2 MB)
#define GMAXR 32                      // gate scratch sized for 32 rows

typedef unsigned short u16;
typedef unsigned int u32;

__device__ __forceinline__ u16 f2bf(float f) {
    union { float f; unsigned u; } v; v.f = f;
    unsigned u = v.u;
    u += 0x7fff + ((u >> 16) & 1);    // RNE
    return (u16)(u >> 16);
}
__device__ __forceinline__ float bf2f(u16 b) {
    union { unsigned u; float f; } v; v.u = ((unsigned)b) << 16;
    return v.f;
}
__device__ __forceinline__ float sigm(float x)  { return 1.f / (1.f + __expf(-x)); }
// tanh(x) = 2*sigmoid(2x)-1 ; safe at extremes
__device__ __forceinline__ float tanhs(float x) { return 2.f / (1.f + __expf(-2.f * x)) - 1.f; }

// ---------------- prep: xe rows + inverse squared norms ----------------
__global__ void prep_kernel(const int* __restrict__ q, const int* __restrict__ a,
                            const float* __restrict__ embed,
                            float* __restrict__ xe_all, float* __restrict__ inv_all) {
    int u = blockIdx.x * 4 + (threadIdx.x >> 6);
    int lane = threadIdx.x & 63;
    if (u >= NU) return;
    int sb = u / LL, t = u % LL;
    int s = sb >> 5, b = sb & 31;
    const int* idx = s ? a : q;
    int e = idx[b * LL + t];
    const float* row = embed + (size_t)e * DD;
    float v0 = row[lane], v1 = row[lane + 64];
    xe_all[(size_t)u * DD + lane] = v0;
    xe_all[(size_t)u * DD + lane + 64] = v1;
    float d = v0 * v0 + v1 * v1;
    #pragma unroll
    for (int o = 32; o; o >>= 1) d += __shfl_down(d, o);
    if (lane == 0) inv_all[u] = 1.f / (d + 1e-4f);
}

// ---------------- layer1 separable gates (xt-only rows, density rank-1) ----------------
// t-parallel: grid (LL, NSB), block 1024. Level rows [r0, r0+nr), all < 63.
// Writes packed (fg|og<<16) u32 plane and packed ic pairs.
__global__ __launch_bounds__(1024)
void sepgates_kernel(const float* __restrict__ xe_all, const float* __restrict__ inv_all,
                     const float* __restrict__ conv_w, const float* __restrict__ conv_b,
                     u32* __restrict__ gfo, u32* __restrict__ gic2,
                     int r0, int nr) {
    const int t = blockIdx.x, sb = blockIdx.y;
    const int tid = threadIdx.x;
    __shared__ float xe_s[132];        // data at [c+1], pads 0
    __shared__ float U[GMAXR][12];
    __shared__ float wls[48];
    float b4[4];
    #pragma unroll
    for (int k = 0; k < 4; ++k) b4[k] = conv_b[k];
    if (tid < 48) wls[tid] = conv_w[tid];
    if (tid < 128) xe_s[tid + 1] = xe_all[((size_t)sb * LL + t) * DD + tid];
    if (tid == 128) { xe_s[0] = 0.f; xe_s[129] = 0.f; xe_s[130] = 0.f; }
    __syncthreads();
    for (int e = tid; e < nr * 12; e += 1024) {
        int lr = e / 12, k = e - lr * 12;
        int g = k / 3, kw = k - g * 3;
        int base = 2 * (r0 + lr) - 1;
        float s = 0.f;
        #pragma unroll
        for (int kh = 0; kh < 4; ++kh) {
            int r = base + kh;
            float v = (r >= 0 && r < 128) ? xe_s[r + 1] : 0.f;
            s += wls[g * 12 + kh * 3 + kw] * v;
        }
        U[lr][k] = s;
    }
    __syncthreads();
    const float invv = inv_all[sb * LL + t];
    const size_t gb = (size_t)(t * NSB + sb) * ((size_t)nr * DD);
    const int nunits = nr * 64;
    for (int u = tid; u < nunits; u += 1024) {
        int lr = u >> 6, cp = u & 63;
        float x0 = xe_s[2 * cp], x1 = xe_s[2 * cp + 1];
        float x2 = xe_s[2 * cp + 2], x3 = xe_s[2 * cp + 3];
        float a[4], c[4];
        #pragma unroll
        for (int g = 0; g < 4; ++g) {
            float u0 = U[lr][g * 3], u1 = U[lr][g * 3 + 1], u2 = U[lr][g * 3 + 2];
            a[g] = b4[g] + invv * (u0 * x0 + u1 * x1 + u2 * x2);
            c[g] = b4[g] + invv * (u0 * x1 + u1 * x2 + u2 * x3);
        }
        float fg0 = sigm(a[0]), ic0 = sigm(a[1]) * tanhs(a[3]), og0 = sigm(a[2]);
        float fg1 = sigm(c[0]), ic1 = sigm(c[1]) * tanhs(c[3]), og1 = sigm(c[2]);
        const int px0 = lr * DD + 2 * cp;
        u32 f0 = (u32)f2bf(fg0) | ((u32)f2bf(og0) << 16);
        u32 f1 = (u32)f2bf(fg1) | ((u32)f2bf(og1) << 16);
        *(uint2*)&gfo[gb + px0] = make_uint2(f0, f1);
        gic2[(gb >> 1) + (px0 >> 1)] = (u32)f2bf(ic0) | ((u32)f2bf(ic1) << 16);
    }
}

// ---------------- generic gates: stage concat window into LDS, conv, pack ----------------
// t-parallel: grid (LL, NSB), block 1024. Level rows [r0, r0+nr), nr<=32.
// Concat row cr: cr<128 -> xt at time t (layer1: density; layer2: h1[t]);
//                cr>=128 -> own h row cr-128 at time t-1 (= slab t; slab 0 zeroed).
__global__ __launch_bounds__(1024)
void gates_kernel(const float* __restrict__ xe_all, const float* __restrict__ inv_all,
                  const float* __restrict__ conv_w, const float* __restrict__ conv_b,
                  const u16* __restrict__ xt_h1,   // layer2: h1 base; layer1: null (density)
                  const u16* __restrict__ h_own,
                  u32* __restrict__ gfo, u32* __restrict__ gic2,
                  int layer, int r0, int nr) {
    const int t = blockIdx.x, sb = blockIdx.y;
    const int tid = threadIdx.x;
    const int rfirst = 2 * r0 - 1, rcount = 2 * nr + 2;
    __shared__ float win[66][132];     // data col c at [c+2]; pads [0..1],[130..131] zero
    __shared__ float xe_s[128];
    float w[48], b4[4];                // uniform -> scalar regs
    #pragma unroll
    for (int k = 0; k < 48; ++k) w[k] = conv_w[layer * 48 + k];
    #pragma unroll
    for (int k = 0; k < 4; ++k) b4[k] = conv_b[layer * 4 + k];
    float invv = 0.f;
    if (layer == 0) {
        for (int e = tid; e < 128; e += 1024)
            xe_s[e] = xe_all[((size_t)sb * LL + t) * DD + e];
        invv = inv_all[sb * LL + t];
    }
    for (int e = tid; e < rcount; e += 1024) {
        win[e][0] = 0.f; win[e][1] = 0.f; win[e][130] = 0.f; win[e][131] = 0.f;
    }
    __syncthreads();                   // xe_s ready
    const u16* xt_base  = xt_h1 ? xt_h1 + (size_t)(t + 1) * SLAB + (size_t)sb * PLANE : nullptr;
    const u16* own_base = h_own + (size_t)t * SLAB + (size_t)sb * PLANE;
    for (int e = tid; e < rcount * 64; e += 1024) {
        int lr = e >> 6, cp = e & 63, cr = rfirst + lr;
        float v0 = 0.f, v1 = 0.f;
        if (cr >= 0) {
            if (cr < 128) {
                if (layer == 0) {
                    float xr = xe_s[cr] * invv;
                    v0 = xr * xe_s[2 * cp]; v1 = xr * xe_s[2 * cp + 1];
                } else {
                    u32 p = *(const u32*)(xt_base + (size_t)cr * DD + 2 * cp);
                    v0 = bf2f((u16)p); v1 = bf2f((u16)(p >> 16));
                }
            } else {
                u32 p = *(const u32*)(own_base + (size_t)(cr - 128) * DD + 2 * cp);
                v0 = bf2f((u16)p); v1 = bf2f((u16)(p >> 16));
            }
        }
        *(float2*)&win[lr][2 * cp + 2] = make_float2(v0, v1);
    }
    __syncthreads();
    const size_t gb = (size_t)(t * NSB + sb) * ((size_t)nr * DD);
    const int nunits = nr * 64;
    for (int u = tid; u < nunits; u += 1024) {
        const int lro = u >> 6, cp = u & 63;
        float a0 = b4[0], a1 = b4[1], a2 = b4[2], a3 = b4[3];
        float c0 = b4[0], c1 = b4[1], c2 = b4[2], c3 = b4[3];
        #pragma unroll
        for (int kh = 0; kh < 4; ++kh) {
            const float* wr = win[2 * lro + kh];
            float2 pA = *(const float2*)&wr[2 * cp];       // cols 2cp-2, 2cp-1
            float2 pB = *(const float2*)&wr[2 * cp + 2];   // cols 2cp, 2cp+1
            float  pC = wr[2 * cp + 4];                    // col 2cp+2
            a0 = fmaf(pA.y, w[kh*3+0], a0); a0 = fmaf(pB.x, w[kh*3+1], a0); a0 = fmaf(pB.y, w[kh*3+2], a0);
            a1 = fmaf(pA.y, w[12+kh*3+0], a1); a1 = fmaf(pB.x, w[12+kh*3+1], a1); a1 = fmaf(pB.y, w[12+kh*3+2], a1);
            a2 = fmaf(pA.y, w[24+kh*3+0], a2); a2 = fmaf(pB.x, w[24+kh*3+1], a2); a2 = fmaf(pB.y, w[24+kh*3+2], a2);
            a3 = fmaf(pA.y, w[36+kh*3+0], a3); a3 = fmaf(pB.x, w[36+kh*3+1], a3); a3 = fmaf(pB.y, w[36+kh*3+2], a3);
            c0 = fmaf(pB.x, w[kh*3+0], c0); c0 = fmaf(pB.y, w[kh*3+1], c0); c0 = fmaf(pC, w[kh*3+2], c0);
            c1 = fmaf(pB.x, w[12+kh*3+0], c1); c1 = fmaf(pB.y, w[12+kh*3+1], c1); c1 = fmaf(pC, w[12+kh*3+2], c1);
            c2 = fmaf(pB.x, w[24+kh*3+0], c2); c2 = fmaf(pB.y, w[24+kh*3+1], c2); c2 = fmaf(pC, w[24+kh*3+2], c2);
            c3 = fmaf(pB.x, w[36+kh*3+0], c3); c3 = fmaf(pB.y, w[36+kh*3+1], c3); c3 = fmaf(pC, w[36+kh*3+2], c3);
        }
        float fg0 = sigm(a0), ic0 = sigm(a1) * tanhs(a3), og0 = sigm(a2);
        float fg1 = sigm(c0), ic1 = sigm(c1) * tanhs(c3), og1 = sigm(c2);
        const int px0 = lro * DD + 2 * cp;
        u32 f0 = (u32)f2bf(fg0) | ((u32)f2bf(og0) << 16);
        u32 f1 = (u32)f2bf(fg1) | ((u32)f2bf(og1) << 16);
        *(uint2*)&gfo[gb + px0] = make_uint2(f0, f1);
        gic2[(gb >> 1) + (px0 >> 1)] = (u32)f2bf(ic0) | ((u32)f2bf(ic1) << 16);
    }
}

// ---------------- scan: pointwise c-recurrence over t ----------------
// grid (nr, NSB), block 128 (one row per block). h slab s holds time s-1.
__global__ __launch_bounds__(128)
void scan_kernel(const u32* __restrict__ gfo, const u16* __restrict__ gic,
                 u16* __restrict__ h, float* __restrict__ pool, int r0, int nr) {
    const int lr = blockIdx.x, sb = blockIdx.y, c = threadIdx.x;
    const size_t step = (size_t)NSB * nr * DD;
    size_t gi = ((size_t)sb * nr + lr) * DD + c;
    u16* hp = h + SLAB + (size_t)sb * PLANE + (size_t)(r0 + lr) * DD + c;
    float cc = 0.f, pr = -1e30f;
    #pragma unroll 4
    for (int t = 0; t < LL; ++t) {
        u32 v = gfo[gi];
        float fg = bf2f((u16)v), og = bf2f((u16)(v >> 16));
        float ic = bf2f(gic[gi]);
        cc = fg * cc + ic;
        float hn = og * tanhs(cc);
        *hp = f2bf(hn);
        pr = fmaxf(pr, hn);
        gi += step; hp += SLAB;
    }
    if (pool) pool[(size_t)sb * PLANE + (size_t)(r0 + lr) * DD + c] = pr;
}

// conv+LSTM update for one tail pixel from the LDS window
__device__ __forceinline__
float tail_px(const float (*wp)[130], const float* wls, const float* bls,
              int lr, int c, float& creg, float& pr) {
    float a0 = bls[0], a1 = bls[1], a2 = bls[2], a3 = bls[3];
    #pragma unroll
    for (int kh = 0; kh < 4; ++kh) {
        #pragma unroll
        for (int kw = 0; kw < 3; ++kw) {
            float v = wp[lr + kh][c + kw];
            a0 = fmaf(v, wls[kh*3+kw], a0);
            a1 = fmaf(v, wls[12+kh*3+kw], a1);
            a2 = fmaf(v, wls[24+kh*3+kw], a2);
            a3 = fmaf(v, wls[36+kh*3+kw], a3);
        }
    }
    float fg = sigm(a0), ig = sigm(a1), og = sigm(a2), cs = tanhs(a3);
    creg = fg * creg + ig * cs;
    float hn = og * tanhs(creg);
    pr = fmaxf(pr, hn);
    return hn;
}

// ---------------- tail rows 123..127: serial t, 5 rows, prefetched staging ----------------
// grid (NSB) x 640. Window h rows 117..128: lr 0..5 = rows 117..122 (staged from
// global, t-1 = slab t), lr 6..10 = own rows 123..127 (LDS ping-pong), lr 11 = zero.
__global__ __launch_bounds__(640)
void tail5_kernel(const u16* __restrict__ hsrc, u16* __restrict__ hdst,
                  float* __restrict__ pool,
                  const float* __restrict__ conv_w, const float* __restrict__ conv_b,
                  int layer) {
    const int sb = blockIdx.x;
    const int tid = threadIdx.x;
    const int slot = tid >> 7;         // 0..4 -> row 123+slot
    const int c = tid & 127;
    const int r = 123 + slot;
    __shared__ float win[2][12][130];  // data at [c+1]; col pads + lr 11 stay zero
    __shared__ float wls[48], bls[4];
    if (tid < 48) wls[tid] = conv_w[layer * 48 + tid];
    if (tid < 4)  bls[tid] = conv_b[layer * 4 + tid];
    for (int e = tid; e < 2 * 12 * 130; e += 640) ((float*)win)[e] = 0.f;

    const bool ldr = tid < 384;        // 6 rows x 64 col-pairs
    const int lrow = tid >> 6;         // 0..5
    const int lcp = tid & 63;
    const u16* gsrc = hsrc + (size_t)sb * PLANE + (size_t)(117 + lrow) * DD + 2 * lcp;
    u32 pre = 0;
    if (ldr) pre = *(const u32*)gsrc;  // t=0: slab 0 (zeroed)

    const int lr0 = 2 * slot;          // window start row for output r
    u16* hd = hdst ? hdst + SLAB + (size_t)sb * PLANE + (size_t)r * DD + c : nullptr;
    float creg = 0.f, pr = -1e30f;

    for (int t = 0; t < LL; ++t) {
        const int p = t & 1;
        __syncthreads();               // prior reads/writes of win[p] done
        if (ldr) {
            win[p][lrow][2 * lcp + 1] = bf2f((u16)pre);
            win[p][lrow][2 * lcp + 2] = bf2f((u16)(pre >> 16));
        }
        __syncthreads();
        if (ldr && t + 1 < LL)         // prefetch next step's rows (hides HBM latency)
            pre = *(const u32*)(gsrc + (size_t)(t + 1) * SLAB);
        float hn = tail_px(win[p], wls, bls, lr0, c, creg, pr);
        win[p ^ 1][6 + slot][c + 1] = hn;   // own h for t+1's window
        if (hd) { *hd = f2bf(hn); hd += SLAB; }
    }
    if (pool) pool[(size_t)sb * PLANE + (size_t)r * DD + c] = pr;
}

// ---------------- final: linear + log_softmax ----------------
__global__ void final_kernel(const float* __restrict__ pool,
                             const float* __restrict__ lin_w,
                             const float* __restrict__ lin_b,
                             float* __restrict__ out) {
    const int b = blockIdx.x;
    const int tid = threadIdx.x;  // 256
    const int DD2 = DD * DD;
    const float* pq = pool + (size_t)b * DD2;
    const float* pa = pool + (size_t)(BB + b) * DD2;
    float s0 = 0.f, s1 = 0.f;
    for (int j = tid; j < DD2; j += 256) {
        float vq = pq[j], va = pa[j];
        s0 += vq * lin_w[j]           + va * lin_w[DD2 + j];
        s1 += vq * lin_w[2 * DD2 + j] + va * lin_w[3 * DD2 + j];
    }
    #pragma unroll
    for (int o = 32; o; o >>= 1) {
        s0 += __shfl_down(s0, o);
        s1 += __shfl_down(s1, o);
    }
    __shared__ float sh0[4], sh1[4];
    int wid = tid >> 6, lane = tid & 63;
    if (lane == 0) { sh0[wid] = s0; sh1[wid] = s1; }
    __syncthreads();
    if (tid == 0) {
        float a0 = sh0[0] + sh0[1] + sh0[2] + sh0[3] + lin_b[0];
        float a1 = sh1[0] + sh1[1] + sh1[2] + sh1[3] + lin_b[1];
        float m = fmaxf(a0, a1);
        float lse = m + logf(expf(a0 - m) + expf(a1 - m));
        out[b * 2 + 0] = a0 - lse;
        out[b * 2 + 1] = a1 - lse;
    }
}

extern "C" void kernel_launch(void* const* d_in, const int* in_sizes, int n_in,
                              void* d_out, int out_size, void* d_ws, size_t ws_size,
                              hipStream_t stream) {
    const int*   q      = (const int*)d_in[0];
    const int*   a      = (const int*)d_in[1];
    const float* embed  = (const float*)d_in[2];
    const float* conv_w = (const float*)d_in[3];
    const float* conv_b = (const float*)d_in[4];
    const float* lin_w  = (const float*)d_in[5];
    const float* lin_b  = (const float*)d_in[6];
    float* out = (float*)d_out;

    // ws: pool 4.2 | xe 1.31 | inv | h1 86 | h2 86 | gfo 52.4 | gic 26.2  => ~256 MB... 
    // gfo/gic sized for GMAXR=32 rows: 40*64*32*128 px -> 52.4MB + 26.2MB (as before).
    float* ws      = (float*)d_ws;
    float* pool    = ws;
    float* xe_all  = pool + (size_t)NSB * PLANE;
    float* inv_all = xe_all + (size_t)NU * DD;
    u16*   h1      = (u16*)(inv_all + NU);
    u16*   h2      = h1 + (size_t)(LL + 1) * SLAB;
    u32*   gfo     = (u32*)(h2 + (size_t)(LL + 1) * SLAB);
    u32*   gic2    = gfo + (size_t)LL * NSB * GMAXR * DD;
    const u16* gic = (const u16*)gic2;

    // zero the t = -1 slabs
    hipMemsetAsync(h1, 0, SLAB * sizeof(u16), stream);
    hipMemsetAsync(h2, 0, SLAB * sizeof(u16), stream);

    prep_kernel<<<(NU + 3) / 4, 256, 0, stream>>>(q, a, embed, xe_all, inv_all);

    // Levels [0,32) [32,63) [63,95) [95,111) [111,119) [119,123); rows 123..127 serial.
    const int levs[6][2] = {{0,32},{32,31},{63,32},{95,16},{111,8},{119,4}};
    const dim3 ggrid(LL, NSB);

    for (int layer = 0; layer < 2; ++layer) {
        const u16* xt = layer ? h1 : nullptr;
        u16* hh       = layer ? h2 : h1;
        float* pl     = layer ? pool : nullptr;
        for (int k = 0; k < 6; ++k) {
            const int r0 = levs[k][0], nr = levs[k][1];
            if (layer == 0 && k < 2) {
                sepgates_kernel<<<ggrid, 1024, 0, stream>>>(
                    xe_all, inv_all, conv_w, conv_b, gfo, gic2, r0, nr);
            } else {
                gates_kernel<<<ggrid, 1024, 0, stream>>>(
                    xe_all, inv_all, conv_w, conv_b, xt, hh,
                    gfo, gic2, layer, r0, nr);
            }
            scan_kernel<<<dim3(nr, NSB), 128, 0, stream>>>(
                gfo, gic, hh, pl, r0, nr);
        }
        tail5_kernel<<<NSB, 640, 0, stream>>>(hh, layer ? nullptr : h1,
                                              pl, conv_w, conv_b, layer);
    }

    final_kernel<<<BB, 256, 0, stream>>>(pool, lin_w, lin_b, out);
}